// Round 7
// baseline (77.688 us; speedup 1.0000x reference)
//
#include <hip/hip_runtime.h>

// ---------------------------------------------------------------------------
// LMU fused cell on MI355X (gfx950).  Round 7: one uniform GEMM, 2 blocks/CU.
//   new_h = sigmoid([x|h|m] @ [Wx|Wh|Wm@AT]^T + u*(Wm@BT)^T)
//   new_m = m @ AT^T + u*BT^T     u = [x|h|m].e  (f32, VALU during staging)
// Grid 768 = 128 M-tiles x (4 new_h slices + 2 new_m slices), all one kernel.
//   full slices: 14 chunks of BK=64 over [x|h|m]; short slices: chunks 0..9
//   register-only (u needs all of A), chunks 10..13 MFMA vs AT^T.
//   A: f32 global -> regs -> bf16 swizzled LDS; B: global_load_lds packed.
//   LDS 64KB dbuf -> 2 blocks/CU; R4-style drain barrier per chunk.
// ---------------------------------------------------------------------------

typedef __bf16 bf16;
typedef bf16  bf16x4 __attribute__((ext_vector_type(4)));
typedef bf16  bf16x8 __attribute__((ext_vector_type(8)));
typedef float f32x4  __attribute__((ext_vector_type(4)));
typedef unsigned short u16;

#define BATCH 16384
// ws offsets (u16 units)
#define WPACK 0          // [896/8][512][8] = 458752  (kk>=80 region = Wm@AT)
#define ATPACK 458752    // [256/8][256][8] = 65536
#define WUOFF 524288     // 512 f32  (1024 u16)
#define EOFF  525312     // 896 f32  (1792 u16)  e = [ex|eh|em]
#define PACK_ITEMS 394624   // 327680 + 65536 + 512 + 896

// LDS (u16): per buffer A [128r][8kq][8] swizzled = 8192, B [8kq][128n][8] = 8192
#define ABUF(c) (((c) & 1) * 16384)
#define BBUF(c) (ABUF(c) + 8192)

__device__ __forceinline__ u16 f2bf(float f) {
  unsigned u = __builtin_bit_cast(unsigned, f);
  u += 0x7FFFu + ((u >> 16) & 1u);   // RNE
  return (u16)(u >> 16);
}

__device__ __forceinline__ void gload16(const u16* g, u16* l) {
  __builtin_amdgcn_global_load_lds(
      (const __attribute__((address_space(1))) unsigned int*)g,
      (__attribute__((address_space(3))) unsigned int*)l, 16, 0, 0);
}

// ---------------- prologue 1: pack Wx|Wh, AT, wu=Wm@BT, e-concat -----------
__global__ __launch_bounds__(256) void lmu_pack(
    const float* __restrict__ Wx, const float* __restrict__ Wh,
    const float* __restrict__ Wm, const float* __restrict__ AT,
    const float* __restrict__ BT, const float* __restrict__ ex,
    const float* __restrict__ eh, const float* __restrict__ em,
    u16* __restrict__ ws) {
  int i = blockIdx.x * 256 + threadIdx.x;
  if (i < 327680) {                     // Wall^T[k][n], k<640
    int j = i & 7, rest = i >> 3;
    int n = rest & 511, kk = rest >> 9;
    int k = kk * 8 + j;
    float v = (k < 128) ? Wx[n * 128 + k] : Wh[n * 512 + (k - 128)];
    ws[WPACK + i] = f2bf(v);
  } else if (i < 393216) {              // atpack[kk][d][j] = AT[d][kk*8+j]
    int t = i - 327680;
    int j = t & 7, rest = t >> 3;
    int d = rest & 255, kk = rest >> 8;
    ws[ATPACK + t] = f2bf(AT[d * 256 + kk * 8 + j]);
  } else if (i < 393728) {              // wu[n] = dot(Wm[n,:], BT)
    int n = i - 393216;
    float s = 0.f;
    for (int k = 0; k < 256; k += 4) {
      float4 wv = *(const float4*)(Wm + (size_t)n * 256 + k);
      float4 bv = *(const float4*)(BT + k);
      s += wv.x * bv.x + wv.y * bv.y + wv.z * bv.z + wv.w * bv.w;
    }
    ((float*)(ws + WUOFF))[n] = s;
  } else if (i < PACK_ITEMS) {          // ef[k] = concat(ex,eh,em) f32
    int k = i - 393728;
    float v = (k < 128) ? ex[k] : (k < 640) ? eh[k - 128] : em[k - 640];
    ((float*)(ws + EOFF))[k] = v;
  }
}

// ---------------- prologue 2: Wm2 = Wm @ AT, bf16-packed (validated) -------
__global__ __launch_bounds__(256) void lmu_wm2(
    const float* __restrict__ Wm, const float* __restrict__ AT,
    u16* __restrict__ ws) {
  __shared__ float wmt[16 * 256];
  const int t = threadIdx.x;
  const int nb = blockIdx.x * 16, db = blockIdx.y * 64;
#pragma unroll
  for (int it = 0; it < 4; ++it) {
    int f = it * 256 + t;
    float4 v = *(const float4*)(Wm + (size_t)(nb + (f >> 6)) * 256 + (f & 63) * 4);
    *(float4*)(wmt + (f >> 6) * 256 + (f & 63) * 4) = v;
  }
  __syncthreads();
  const int d = db + (t & 63);
  const int nn = (t >> 6) * 4;
  float acc[4] = {0.f, 0.f, 0.f, 0.f};
  for (int k = 0; k < 256; ++k) {
    float atv = AT[(size_t)k * 256 + d];
#pragma unroll
    for (int i2 = 0; i2 < 4; ++i2) acc[i2] += wmt[(nn + i2) * 256 + k] * atv;
  }
  const int kk = 80 + (d >> 3), j = d & 7;
#pragma unroll
  for (int i2 = 0; i2 < 4; ++i2)
    ws[WPACK + ((size_t)kk * 512 + (nb + nn + i2)) * 8 + j] = f2bf(acc[i2]);
}

// ---------------- main GEMM -------------------------------------------------
__global__ __launch_bounds__(512, 4) void lmu_gemm(
    const float* __restrict__ x, const float* __restrict__ h,
    const float* __restrict__ m, const float* __restrict__ BT,
    const u16* __restrict__ ws, float* __restrict__ out) {
  __shared__ __align__(16) u16 smem[2 * 16384];
  const int tid  = threadIdx.x;
  const int lane = tid & 63;
  const int w    = tid >> 6;     // 0..7
  const int wr   = w >> 1;       // 0..3 : 32-row slice
  const int wc   = w & 1;        // 0..1 : 64-col slice
  const int lm   = lane & 15;
  const int kg   = lane >> 4;
  // swizzle: all 6 N-slices of an M-tile on one XCD
  const int bid  = blockIdx.x;
  const int g    = bid >> 3;             // 0..95
  const int nsl  = g >> 4;               // 0..5  (>=4 -> new_m slice)
  const int mi   = ((g & 15) << 3) | (bid & 7);  // 0..127
  const int b0   = mi * 128;
  const bool full = nsl < 4;

  const u16* wpk = ws + WPACK;
  const u16* atp = ws + ATPACK;
  const float* ef = (const float*)(ws + EOFF);

  const int r16 = tid >> 4;      // staging row base 0..31
  const int c4  = tid & 15;      // staging col-group (4 f32)

  f32x4 acc[2][4];
#pragma unroll
  for (int mt = 0; mt < 2; ++mt)
#pragma unroll
    for (int ct = 0; ct < 4; ++ct) acc[mt][ct] = (f32x4){0.f, 0.f, 0.f, 0.f};
  float upart[4] = {0.f, 0.f, 0.f, 0.f};
  float4 av[4], ev;

  auto aload = [&](int c) {      // coalesced: 16 thr x 16B per row
    const float* base;
    int stride, off;
    if (c < 2)       { base = x; stride = 128; off = c * 64; }
    else if (c < 10) { base = h; stride = 512; off = (c - 2) * 64; }
    else             { base = m; stride = 256; off = (c - 10) * 64; }
#pragma unroll
    for (int ph = 0; ph < 4; ++ph)
      av[ph] = *(const float4*)(base + (size_t)(b0 + ph * 32 + r16) * stride + off + c4 * 4);
    ev = *(const float4*)(ef + c * 64 + c4 * 4);
  };
  auto udot = [&]() {
#pragma unroll
    for (int ph = 0; ph < 4; ++ph)
      upart[ph] += av[ph].x * ev.x + av[ph].y * ev.y + av[ph].z * ev.z + av[ph].w * ev.w;
  };
  auto commit = [&](int c) {     // A LDS: row*64 + (kq^(row&7))*8 + jhalf
    u16* bufA = smem + ABUF(c);
    const int kq = c4 >> 1, jh = (c4 & 1) * 4;
#pragma unroll
    for (int ph = 0; ph < 4; ++ph) {
      int row = ph * 32 + r16;
      bf16x4 p = {(bf16)av[ph].x, (bf16)av[ph].y, (bf16)av[ph].z, (bf16)av[ph].w};
      *(bf16x4*)(bufA + row * 64 + ((kq ^ (row & 7)) << 3) + jh) = p;
    }
  };
  auto bstage = [&](int c) {
    u16* bufB = smem + BBUF(c);
#pragma unroll
    for (int ph = 0; ph < 2; ++ph) {
      int i = ph * 512 + tid;
      int kk = i >> 7, n = i & 127;
      const u16* src = full
          ? wpk + ((size_t)(c * 8 + kk) * 512 + nsl * 128 + n) * 8
          : atp + ((size_t)((c - 10) * 8 + kk) * 256 + (nsl - 4) * 128 + n) * 8;
      gload16(src, bufB + i * 8);
    }
  };
  auto mma = [&](int c) {
    const u16* bufA = smem + ABUF(c);
    const u16* bufB = smem + BBUF(c);
#pragma unroll
    for (int ks = 0; ks < 2; ++ks) {
      const int kq = ks * 4 + kg;
      bf16x8 a[2];
#pragma unroll
      for (int mt = 0; mt < 2; ++mt) {
        int row = wr * 32 + mt * 16 + lm;
        a[mt] = *(const bf16x8*)(bufA + row * 64 + ((kq ^ (row & 7)) << 3));
      }
#pragma unroll
      for (int ct = 0; ct < 4; ++ct) {
        bf16x8 b = *(const bf16x8*)(bufB + (kq * 128 + wc * 64 + ct * 16 + lm) * 8);
#pragma unroll
        for (int mt = 0; mt < 2; ++mt)
          acc[mt][ct] = __builtin_amdgcn_mfma_f32_16x16x32_bf16(a[mt], b, acc[mt][ct], 0, 0, 0);
      }
    }
  };

  if (full) {
    aload(0); bstage(0); udot(); commit(0);
    __syncthreads();
#pragma unroll
    for (int c = 0; c < 14; ++c) {
      if (c < 13) { aload(c + 1); bstage(c + 1); }
      mma(c);
      if (c < 13) { udot(); commit(c + 1); }
      __syncthreads();
    }
  } else {
    // chunks 0..9: register-only streaming (u needs all of A)
#pragma unroll 2
    for (int c = 0; c < 10; ++c) { aload(c); udot(); }
    aload(10); bstage(10); udot(); commit(10);
    __syncthreads();
#pragma unroll
    for (int c = 10; c < 14; ++c) {
      if (c < 13) { aload(c + 1); bstage(c + 1); }
      mma(c);
      if (c < 13) { udot(); commit(c + 1); }
      __syncthreads();
    }
  }

  // ---- u exchange: reduce over 16 col-groups, park in dead LDS ----
  float* uL = (float*)smem;   // ABUF(0) region, dead after final barrier
  float s0 = upart[0], s1 = upart[1], s2 = upart[2], s3 = upart[3];
#pragma unroll
  for (int d = 1; d < 16; d <<= 1) {
    s0 += __shfl_xor(s0, d);
    s1 += __shfl_xor(s1, d);
    s2 += __shfl_xor(s2, d);
    s3 += __shfl_xor(s3, d);
  }
  if (c4 == 0) {
    uL[0 * 32 + r16] = s0;
    uL[1 * 32 + r16] = s1;
    uL[2 * 32 + r16] = s2;
    uL[3 * 32 + r16] = s3;
  }
  __syncthreads();

  // ---- epilogue ----
  const float* wuf = (const float*)(ws + WUOFF);
  float cv[4];
#pragma unroll
  for (int ct = 0; ct < 4; ++ct)
    cv[ct] = full ? wuf[nsl * 128 + wc * 64 + ct * 16 + lm]
                  : BT[(nsl - 4) * 128 + wc * 64 + ct * 16 + lm];
  float* outm = out + (size_t)BATCH * 512;
#pragma unroll
  for (int mt = 0; mt < 2; ++mt)
#pragma unroll
    for (int j = 0; j < 4; ++j) {
      int rl = wr * 32 + mt * 16 + kg * 4 + j;
      size_t row = (size_t)(b0 + rl);
      float uv = uL[rl];
      if (full) {
#pragma unroll
        for (int ct = 0; ct < 4; ++ct) {
          float v = acc[mt][ct][j] + uv * cv[ct];
          out[row * 512 + nsl * 128 + wc * 64 + ct * 16 + lm] = 1.0f / (1.0f + __expf(-v));
        }
      } else {
#pragma unroll
        for (int ct = 0; ct < 4; ++ct)
          outm[row * 256 + (nsl - 4) * 128 + wc * 64 + ct * 16 + lm] =
              acc[mt][ct][j] + uv * cv[ct];
      }
    }
}

extern "C" void kernel_launch(void* const* d_in, const int* in_sizes, int n_in,
                              void* d_out, int out_size, void* d_ws, size_t ws_size,
                              hipStream_t stream) {
  const float* x  = (const float*)d_in[0];
  const float* h  = (const float*)d_in[1];
  const float* m  = (const float*)d_in[2];
  const float* Wx = (const float*)d_in[3];
  const float* Wh = (const float*)d_in[4];
  const float* Wm = (const float*)d_in[5];
  const float* ex = (const float*)d_in[6];
  const float* eh = (const float*)d_in[7];
  const float* em = (const float*)d_in[8];
  const float* AT = (const float*)d_in[9];
  const float* BT = (const float*)d_in[10];
  float* out = (float*)d_out;
  u16* ws = (u16*)d_ws;   // uses ~1.06 MB

  lmu_pack<<<(PACK_ITEMS + 255) / 256, 256, 0, stream>>>(Wx, Wh, Wm, AT, BT, ex, eh, em, ws);
  lmu_wm2<<<dim3(32, 4), 256, 0, stream>>>(Wm, AT, ws);
  lmu_gemm<<<768, 512, 0, stream>>>(x, h, m, BT, ws, out);
}

// Round 8
// 72.286 us; speedup vs baseline: 1.0747x; 1.0747x over previous
//
#include <hip/hip_runtime.h>

// ---------------------------------------------------------------------------
// LMU fused cell on MI355X (gfx950).  Round 8: R4 skeleton, overheads removed.
//   new_h = sigmoid([x|h|m] @ [Wx|Wh|Wm@AT]^T + u*(Wm@BT)^T)
//   new_m = m @ AT^T + u*BT^T     u = [x|h|m].e  (f32 exact, in prep)
// K0 (lmu_wpack): weights -> bf16 B-layout; Wm2=Wm@AT; wu=Wm@BT. (merged)
// K1 (lmu_prep):  x,h,m f32 -> bf16 packs (L3-resident ws) + u[16384] f32.
// K2 (lmu_gemm):  grid 768 = 128 M-tiles x (4 new_h + 2 new_m slices).
//   BM=128, BN=128, BK=64; A and B both via global_load_lds, packed LDS,
//   64KB dbuf -> 2 blocks/CU; drain barrier per chunk (R4-proven).
//   Short slices run 4 chunks (m-part vs AT^T).
// ---------------------------------------------------------------------------

typedef __bf16 bf16;
typedef bf16  bf16x8 __attribute__((ext_vector_type(8)));
typedef float f32x4  __attribute__((ext_vector_type(4)));
typedef unsigned short u16;

#define BATCH 16384
// ws offsets (u16 units)
#define WPACK 0            // [896/8][512][8] = 458752  (kk>=80 = Wm@AT)
#define ATPACK 458752      // [256/8][256][8] = 65536
#define WUOFF 524288       // 512 f32  (1024 u16)
#define UOFF  525312       // 16384 f32 (32768 u16)
#define XPACK 558080       // 16384*128
#define HPACK 2655232      // 16384*512
#define MPACK 11043840     // 16384*256
// end: 15,238,144 u16 = ~30.5 MB

#define PACK_ITEMS 393728  // 327680 + 65536 + 512
#define PACK_BLOCKS 1538   // ceil(PACK_ITEMS/256)
#define WM2_BLOCKS 128

__device__ __forceinline__ u16 f2bf(float f) {
  unsigned u = __builtin_bit_cast(unsigned, f);
  u += 0x7FFFu + ((u >> 16) & 1u);   // RNE
  return (u16)(u >> 16);
}

__device__ __forceinline__ void gload16(const u16* g, u16* l) {
  __builtin_amdgcn_global_load_lds(
      (const __attribute__((address_space(1))) unsigned int*)g,
      (__attribute__((address_space(3))) unsigned int*)l, 16, 0, 0);
}

// ---------------- K0: merged weight prep ------------------------------------
__global__ __launch_bounds__(256) void lmu_wpack(
    const float* __restrict__ Wx, const float* __restrict__ Wh,
    const float* __restrict__ Wm, const float* __restrict__ AT,
    const float* __restrict__ BT, u16* __restrict__ ws) {
  __shared__ float wmt[16 * 256];
  const int bx = blockIdx.x;
  if (bx < PACK_BLOCKS) {
    int i = bx * 256 + threadIdx.x;
    if (i < 327680) {                     // Wall^T[k][n], k<640
      int j = i & 7, rest = i >> 3;
      int n = rest & 511, kk = rest >> 9;
      int k = kk * 8 + j;
      float v = (k < 128) ? Wx[n * 128 + k] : Wh[n * 512 + (k - 128)];
      ws[WPACK + i] = f2bf(v);
    } else if (i < 393216) {              // atpack[kk][d][j] = AT[d][kk*8+j]
      int t = i - 327680;
      int j = t & 7, rest = t >> 3;
      int d = rest & 255, kk = rest >> 8;
      ws[ATPACK + t] = f2bf(AT[d * 256 + kk * 8 + j]);
    } else if (i < PACK_ITEMS) {          // wu[n] = dot(Wm[n,:], BT)
      int n = i - 393216;
      float s = 0.f;
      for (int k = 0; k < 256; k += 4) {
        float4 wv = *(const float4*)(Wm + (size_t)n * 256 + k);
        float4 bv = *(const float4*)(BT + k);
        s += wv.x * bv.x + wv.y * bv.y + wv.z * bv.z + wv.w * bv.w;
      }
      ((float*)(ws + WUOFF))[n] = s;
    }
  } else {                                // Wm2 = Wm @ AT (16r x 64d tiles)
    const int wq = bx - PACK_BLOCKS;      // 0..127
    const int t = threadIdx.x;
    const int nb = (wq & 31) * 16, db = (wq >> 5) * 64;
#pragma unroll
    for (int it = 0; it < 4; ++it) {
      int f = it * 256 + t;
      float4 v = *(const float4*)(Wm + (size_t)(nb + (f >> 6)) * 256 + (f & 63) * 4);
      *(float4*)(wmt + (f >> 6) * 256 + (f & 63) * 4) = v;
    }
    __syncthreads();
    const int d = db + (t & 63);
    const int nn = (t >> 6) * 4;
    float acc[4] = {0.f, 0.f, 0.f, 0.f};
    for (int k = 0; k < 256; ++k) {
      float atv = AT[(size_t)k * 256 + d];
#pragma unroll
      for (int i2 = 0; i2 < 4; ++i2) acc[i2] += wmt[(nn + i2) * 256 + k] * atv;
    }
    const int kk = 80 + (d >> 3), j = d & 7;
#pragma unroll
    for (int i2 = 0; i2 < 4; ++i2)
      ws[WPACK + ((size_t)kk * 512 + (nb + nn + i2)) * 8 + j] = f2bf(acc[i2]);
  }
}

// ---------------- K1: A bf16 packs + u (f32 exact) --------------------------
// one wave per row; lane covers float2 slots lane + 64j, j=0..6 over [x|h|m].
__global__ __launch_bounds__(512, 4) void lmu_prep(
    const float* __restrict__ x, const float* __restrict__ h,
    const float* __restrict__ m, const float* __restrict__ ex,
    const float* __restrict__ eh, const float* __restrict__ em,
    u16* __restrict__ ws) {
  const int lane = threadIdx.x & 63;
  const int row  = blockIdx.x * 8 + (threadIdx.x >> 6);
  float* uout = (float*)(ws + UOFF);
  u16* xp = ws + XPACK;
  u16* hp = ws + HPACK;
  u16* mp = ws + MPACK;
  float s = 0.f;
#pragma unroll
  for (int j = 0; j < 7; ++j) {
    int f2i = j * 64 + lane;              // float2 index over 448 = [64x|256h|128m]
    float2 av, ev;
    u16* dst;
    if (f2i < 64)       { int c = f2i * 2;
      av = *(const float2*)(x + (size_t)row * 128 + c); ev = *(const float2*)(ex + c);
      dst = xp + (size_t)row * 128 + c; }
    else if (f2i < 320) { int c = (f2i - 64) * 2;
      av = *(const float2*)(h + (size_t)row * 512 + c); ev = *(const float2*)(eh + c);
      dst = hp + (size_t)row * 512 + c; }
    else                { int c = (f2i - 320) * 2;
      av = *(const float2*)(m + (size_t)row * 256 + c); ev = *(const float2*)(em + c);
      dst = mp + (size_t)row * 256 + c; }
    s += av.x * ev.x + av.y * ev.y;
    unsigned pk = ((unsigned)f2bf(av.y) << 16) | f2bf(av.x);
    *(unsigned*)dst = pk;
  }
#pragma unroll
  for (int d = 1; d < 64; d <<= 1) s += __shfl_xor(s, d);
  if (lane == 0) uout[row] = s;
}

// ---------------- K2: main GEMM ----------------------------------------------
// grid 768; bid -> (xcd = bid&7, j = bid>>3); mi = xcd + 8*(j/6); nsl = j%6.
// Slices of one M-tile are on consecutive bids of one XCD (L2 A-reuse).
__global__ __launch_bounds__(512, 4) void lmu_gemm(
    const u16* __restrict__ ws, const float* __restrict__ BT,
    float* __restrict__ out) {
  __shared__ __align__(16) u16 smem[2 * 16384];   // 64KB: 2 x (A 8192 | B 8192)
  const int tid  = threadIdx.x;
  const int lane = tid & 63;
  const int w    = tid >> 6;     // 0..7
  const int wr   = w >> 1;       // 0..3 : 32-row slice
  const int wc   = w & 1;        // 0..1 : 64-col slice
  const int lm   = lane & 15;
  const int kg   = lane >> 4;
  const int bid  = blockIdx.x;
  const int j    = bid >> 3;
  const int mi   = (bid & 7) + 8 * (j / 6);   // 0..127
  const int nsl  = j % 6;                      // 0..3 new_h, 4..5 new_m
  const int b0   = mi * 128;
  const bool full = nsl < 4;
  const int nchunk = full ? 14 : 4;

  const u16* wpk = ws + WPACK;
  const u16* atp = ws + ATPACK;
  const u16* xp  = ws + XPACK;
  const u16* hp  = ws + HPACK;
  const u16* mp  = ws + MPACK;

  f32x4 acc[2][4];
#pragma unroll
  for (int mt = 0; mt < 2; ++mt)
#pragma unroll
    for (int ct = 0; ct < 4; ++ct) acc[mt][ct] = (f32x4){0.f, 0.f, 0.f, 0.f};

  auto stage = [&](int c) {
    u16* buf = smem + (c & 1) * 16384;
    // A chunk: 128 rows x 64 k bf16 = 16KB -> LDS [kb][r][8]
#pragma unroll
    for (int ph = 0; ph < 2; ++ph) {
      int i = ph * 512 + tid;
      int kb = i >> 7, r = i & 127;
      const u16* src;
      if (full) {
        if (c < 2)       src = xp + (size_t)(b0 + r) * 128 + c * 64 + kb * 8;
        else if (c < 10) src = hp + (size_t)(b0 + r) * 512 + (c - 2) * 64 + kb * 8;
        else             src = mp + (size_t)(b0 + r) * 256 + (c - 10) * 64 + kb * 8;
      } else {
        src = mp + (size_t)(b0 + r) * 256 + c * 64 + kb * 8;
      }
      gload16(src, buf + i * 8);
    }
    // B chunk: 8 kk x 128 n x 8 = 16KB -> LDS [kk][n][8]
#pragma unroll
    for (int ph = 0; ph < 2; ++ph) {
      int i = ph * 512 + tid;
      int kk = i >> 7, n = i & 127;
      const u16* src = full
          ? wpk + ((size_t)(c * 8 + kk) * 512 + nsl * 128 + n) * 8
          : atp + ((size_t)(c * 8 + kk) * 256 + (nsl - 4) * 128 + n) * 8;
      gload16(src, buf + 8192 + i * 8);
    }
  };
  auto mma = [&](int c) {
    const u16* bufA = smem + (c & 1) * 16384;
    const u16* bufB = bufA + 8192;
#pragma unroll
    for (int ks = 0; ks < 2; ++ks) {
      const int kq = ks * 4 + kg;
      bf16x8 a[2];
#pragma unroll
      for (int mt = 0; mt < 2; ++mt)
        a[mt] = *(const bf16x8*)(bufA + (kq * 128 + wr * 32 + mt * 16 + lm) * 8);
#pragma unroll
      for (int ct = 0; ct < 4; ++ct) {
        bf16x8 b = *(const bf16x8*)(bufB + (kq * 128 + wc * 64 + ct * 16 + lm) * 8);
#pragma unroll
        for (int mt = 0; mt < 2; ++mt)
          acc[mt][ct] = __builtin_amdgcn_mfma_f32_16x16x32_bf16(a[mt], b, acc[mt][ct], 0, 0, 0);
      }
    }
  };

  stage(0);
  __syncthreads();
#pragma unroll 2
  for (int c = 0; c < nchunk; ++c) {
    if (c + 1 < nchunk) stage(c + 1);   // issue next chunk first (overlap)
    mma(c);
    __syncthreads();                     // drain (R4-proven)
  }

  // ---- epilogue ----
  const float* uf  = (const float*)(ws + UOFF);
  const float* wuf = (const float*)(ws + WUOFF);
  float cv[4];
#pragma unroll
  for (int ct = 0; ct < 4; ++ct)
    cv[ct] = full ? wuf[nsl * 128 + wc * 64 + ct * 16 + lm]
                  : BT[(nsl - 4) * 128 + wc * 64 + ct * 16 + lm];
  float* outm = out + (size_t)BATCH * 512;
#pragma unroll
  for (int mt = 0; mt < 2; ++mt)
#pragma unroll
    for (int jj = 0; jj < 4; ++jj) {
      int rl = wr * 32 + mt * 16 + kg * 4 + jj;
      size_t row = (size_t)(b0 + rl);
      float uv = uf[row];
      if (full) {
#pragma unroll
        for (int ct = 0; ct < 4; ++ct) {
          float v = acc[mt][ct][jj] + uv * cv[ct];
          out[row * 512 + nsl * 128 + wc * 64 + ct * 16 + lm] = 1.0f / (1.0f + __expf(-v));
        }
      } else {
#pragma unroll
        for (int ct = 0; ct < 4; ++ct)
          outm[row * 256 + (nsl - 4) * 128 + wc * 64 + ct * 16 + lm] =
              acc[mt][ct][jj] + uv * cv[ct];
      }
    }
}

extern "C" void kernel_launch(void* const* d_in, const int* in_sizes, int n_in,
                              void* d_out, int out_size, void* d_ws, size_t ws_size,
                              hipStream_t stream) {
  const float* x  = (const float*)d_in[0];
  const float* h  = (const float*)d_in[1];
  const float* m  = (const float*)d_in[2];
  const float* Wx = (const float*)d_in[3];
  const float* Wh = (const float*)d_in[4];
  const float* Wm = (const float*)d_in[5];
  const float* ex = (const float*)d_in[6];
  const float* eh = (const float*)d_in[7];
  const float* em = (const float*)d_in[8];
  const float* AT = (const float*)d_in[9];
  const float* BT = (const float*)d_in[10];
  float* out = (float*)d_out;
  u16* ws = (u16*)d_ws;   // uses ~30.5 MB

  lmu_wpack<<<PACK_BLOCKS + WM2_BLOCKS, 256, 0, stream>>>(Wx, Wh, Wm, AT, BT, ws);
  lmu_prep<<<BATCH / 8, 512, 0, stream>>>(x, h, m, ex, eh, em, ws);
  lmu_gemm<<<768, 512, 0, stream>>>(ws, BT, out);
}

// Round 9
// 65.287 us; speedup vs baseline: 1.1900x; 1.1072x over previous
//
#include <hip/hip_runtime.h>

// ---------------------------------------------------------------------------
// LMU fused cell on MI355X (gfx950).  Round 9: R4 skeleton + 32x32 MFMA.
//   new_h = sigmoid([x|h|m] @ [Wx|Wh|Wm@AT]^T + u*(Wm@BT)^T)
//   new_m = m @ AT^T + u*BT^T     u = [x|h|m].e  (f32 exact, in prep)
// K0 lmu_wpack: weights -> bf16 B-layout [kk][n][8]; Wm2=Wm@AT; wu=Wm@BT.
// K1 lmu_prep:  x|h|m f32 -> one bf16 A-pack [16384][896] + u[16384] f32.
// K2 lmu_gemm:  512 uniform blocks = 128 M-tiles x 4 N-slices (2/CU, 1 round).
//   256 thr, 4 waves of 64x64 (mfma_f32_32x32x16_bf16), BK=64 x 14 chunks,
//   A+B via global_load_lds into 64KB dbuf, drain barrier per chunk;
//   side new_m (chunks 10-13) with B-frags per-lane from L2.
// ---------------------------------------------------------------------------

typedef __bf16 bf16;
typedef bf16  bf16x8 __attribute__((ext_vector_type(8)));
typedef float f32x16 __attribute__((ext_vector_type(16)));
typedef unsigned short u16;

#define BATCH 16384
// ws offsets (u16 units)
#define WPACK 0            // [896/8][512][8] = 458752  (kk>=80 = Wm@AT)
#define ATPACK 458752      // [256/8][256][8] = 65536
#define WUOFF 524288       // 512 f32  (1024 u16)
#define UOFF  525312       // 16384 f32 (32768 u16)
#define APACK 558080       // 16384*896 u16
// end: 15,238,144 u16 = ~30.5 MB

#define PACK_ITEMS 393728  // 327680 + 65536 + 512
#define PACK_BLOCKS 1538
#define WM2_BLOCKS 128

__device__ __forceinline__ u16 f2bf(float f) {
  unsigned u = __builtin_bit_cast(unsigned, f);
  u += 0x7FFFu + ((u >> 16) & 1u);   // RNE
  return (u16)(u >> 16);
}

__device__ __forceinline__ void gload16(const u16* g, u16* l) {
  __builtin_amdgcn_global_load_lds(
      (const __attribute__((address_space(1))) unsigned int*)g,
      (__attribute__((address_space(3))) unsigned int*)l, 16, 0, 0);
}

// ---------------- K0: merged weight prep (validated R8) ---------------------
__global__ __launch_bounds__(256) void lmu_wpack(
    const float* __restrict__ Wx, const float* __restrict__ Wh,
    const float* __restrict__ Wm, const float* __restrict__ AT,
    const float* __restrict__ BT, u16* __restrict__ ws) {
  __shared__ float wmt[16 * 256];
  const int bx = blockIdx.x;
  if (bx < PACK_BLOCKS) {
    int i = bx * 256 + threadIdx.x;
    if (i < 327680) {                     // Wall^T[k][n], k<640
      int j = i & 7, rest = i >> 3;
      int n = rest & 511, kk = rest >> 9;
      int k = kk * 8 + j;
      float v = (k < 128) ? Wx[n * 128 + k] : Wh[n * 512 + (k - 128)];
      ws[WPACK + i] = f2bf(v);
    } else if (i < 393216) {              // atpack[kk][d][j] = AT[d][kk*8+j]
      int t = i - 327680;
      int j = t & 7, rest = t >> 3;
      int d = rest & 255, kk = rest >> 8;
      ws[ATPACK + t] = f2bf(AT[d * 256 + kk * 8 + j]);
    } else if (i < PACK_ITEMS) {          // wu[n] = dot(Wm[n,:], BT)
      int n = i - 393216;
      float s = 0.f;
      for (int k = 0; k < 256; k += 4) {
        float4 wv = *(const float4*)(Wm + (size_t)n * 256 + k);
        float4 bv = *(const float4*)(BT + k);
        s += wv.x * bv.x + wv.y * bv.y + wv.z * bv.z + wv.w * bv.w;
      }
      ((float*)(ws + WUOFF))[n] = s;
    }
  } else {                                // Wm2 = Wm @ AT (16r x 64d tiles)
    const int wq = bx - PACK_BLOCKS;
    const int t = threadIdx.x;
    const int nb = (wq & 31) * 16, db = (wq >> 5) * 64;
#pragma unroll
    for (int it = 0; it < 4; ++it) {
      int f = it * 256 + t;
      float4 v = *(const float4*)(Wm + (size_t)(nb + (f >> 6)) * 256 + (f & 63) * 4);
      *(float4*)(wmt + (f >> 6) * 256 + (f & 63) * 4) = v;
    }
    __syncthreads();
    const int d = db + (t & 63);
    const int nn = (t >> 6) * 4;
    float acc[4] = {0.f, 0.f, 0.f, 0.f};
    for (int k = 0; k < 256; ++k) {
      float atv = AT[(size_t)k * 256 + d];
#pragma unroll
      for (int i2 = 0; i2 < 4; ++i2) acc[i2] += wmt[(nn + i2) * 256 + k] * atv;
    }
    const int kk = 80 + (d >> 3), j = d & 7;
#pragma unroll
    for (int i2 = 0; i2 < 4; ++i2)
      ws[WPACK + ((size_t)kk * 512 + (nb + nn + i2)) * 8 + j] = f2bf(acc[i2]);
  }
}

// ---------------- K1: A-pack [row][896] bf16 + u (f32 exact) ----------------
// wave per row; lane covers float4 slot lane+64j, j=0..3 (224 slots).
__global__ __launch_bounds__(256) void lmu_prep(
    const float* __restrict__ x, const float* __restrict__ h,
    const float* __restrict__ m, const float* __restrict__ ex,
    const float* __restrict__ eh, const float* __restrict__ em,
    u16* __restrict__ ws) {
  const int lane = threadIdx.x & 63;
  const int row  = blockIdx.x * 4 + (threadIdx.x >> 6);
  u16* ap = ws + APACK + (size_t)row * 896;
  float s = 0.f;
#pragma unroll
  for (int j = 0; j < 4; ++j) {
    int slot = j * 64 + lane;
    if (slot < 224) {
      float4 a, e;
      if (slot < 32)       { int c = slot * 4;
        a = *(const float4*)(x + (size_t)row * 128 + c); e = *(const float4*)(ex + c); }
      else if (slot < 160) { int c = (slot - 32) * 4;
        a = *(const float4*)(h + (size_t)row * 512 + c); e = *(const float4*)(eh + c); }
      else                 { int c = (slot - 160) * 4;
        a = *(const float4*)(m + (size_t)row * 256 + c); e = *(const float4*)(em + c); }
      s += a.x * e.x + a.y * e.y + a.z * e.z + a.w * e.w;
      unsigned long long pk =
          (unsigned long long)f2bf(a.x)
        | ((unsigned long long)f2bf(a.y) << 16)
        | ((unsigned long long)f2bf(a.z) << 32)
        | ((unsigned long long)f2bf(a.w) << 48);
      *(unsigned long long*)(ap + slot * 4) = pk;
    }
  }
#pragma unroll
  for (int d = 1; d < 64; d <<= 1) s += __shfl_xor(s, d);
  if (lane == 0) ((float*)(ws + UOFF))[row] = s;
}

// ---------------- K2: main GEMM ----------------------------------------------
// grid 512, 256 thr (4 waves of 64x64). LDS 64KB: 2 x (A 16KB | B 16KB).
__global__ __launch_bounds__(256, 2) void lmu_gemm(
    const u16* __restrict__ ws, const float* __restrict__ BT,
    float* __restrict__ out) {
  __shared__ __align__(16) u16 smem[2 * 16384];
  const int tid  = threadIdx.x;
  const int lane = tid & 63;
  const int w    = tid >> 6;     // 0..3
  const int wr   = w >> 1;       // 0..1 : 64-row half
  const int wc   = w & 1;        // 0..1 : 64-col half
  const int l31  = lane & 31;
  const int kh   = lane >> 5;    // k-half 0..1
  const int bid  = blockIdx.x;
  const int xcd  = bid & 7;
  const int q    = bid >> 3;               // 0..63
  const int nsl  = q & 3;                  // N-slice 0..3
  const int mi   = xcd * 16 + (q >> 2);    // 0..127 (4 slices of mi co-XCD)
  const int b0   = mi * 128;

  const u16* wpk = ws + WPACK;
  const u16* atp = ws + ATPACK;
  const u16* ap  = ws + APACK;

  f32x16 acc[2][2];   // new_h: (mt 32r) x (nt 32c) tiles
  f32x16 acc2[2];     // new_m: (mt 32r) x 32c
#pragma unroll
  for (int mt = 0; mt < 2; ++mt) {
#pragma unroll
    for (int nt = 0; nt < 2; ++nt)
#pragma unroll
      for (int r2 = 0; r2 < 16; ++r2) acc[mt][nt][r2] = 0.f;
#pragma unroll
    for (int r2 = 0; r2 < 16; ++r2) acc2[mt][r2] = 0.f;
  }

  auto stage = [&](int c) {
    u16* buf = smem + (c & 1) * 16384;
    // A: 128r x 64k -> [kb][r][8]
#pragma unroll
    for (int ph = 0; ph < 4; ++ph) {
      int i = ph * 256 + tid;
      int kb = i >> 7, r = i & 127;
      gload16(ap + (size_t)(b0 + r) * 896 + c * 64 + kb * 8, buf + i * 8);
    }
    // B: [kk][n][8], n = nsl*128 + (i&127)
#pragma unroll
    for (int ph = 0; ph < 4; ++ph) {
      int i = ph * 256 + tid;
      int kb = i >> 7, n = i & 127;
      gload16(wpk + ((size_t)(c * 8 + kb) * 512 + nsl * 128 + n) * 8,
              buf + 8192 + i * 8);
    }
  };
  auto mma = [&](int c) {
    const u16* bufA = smem + (c & 1) * 16384;
    const u16* bufB = bufA + 8192;
#pragma unroll
    for (int ks = 0; ks < 4; ++ks) {
      const int kk = ks * 2 + kh;
      bf16x8 a0 = *(const bf16x8*)(bufA + (kk * 128 + wr * 64 + l31) * 8);
      bf16x8 a1 = *(const bf16x8*)(bufA + (kk * 128 + wr * 64 + 32 + l31) * 8);
      bf16x8 b0 = *(const bf16x8*)(bufB + (kk * 128 + wc * 64 + l31) * 8);
      bf16x8 b1 = *(const bf16x8*)(bufB + (kk * 128 + wc * 64 + 32 + l31) * 8);
      acc[0][0] = __builtin_amdgcn_mfma_f32_32x32x16_bf16(a0, b0, acc[0][0], 0, 0, 0);
      acc[0][1] = __builtin_amdgcn_mfma_f32_32x32x16_bf16(a0, b1, acc[0][1], 0, 0, 0);
      acc[1][0] = __builtin_amdgcn_mfma_f32_32x32x16_bf16(a1, b0, acc[1][0], 0, 0, 0);
      acc[1][1] = __builtin_amdgcn_mfma_f32_32x32x16_bf16(a1, b1, acc[1][1], 0, 0, 0);
      if (c >= 10) {   // new_m side-GEMM: B-frag per-lane from L2-hot atpack
        bf16x8 s0 = *(const bf16x8*)(atp +
            ((size_t)((c - 10) * 8 + kk) * 256 + nsl * 64 + wc * 32 + l31) * 8);
        acc2[0] = __builtin_amdgcn_mfma_f32_32x32x16_bf16(a0, s0, acc2[0], 0, 0, 0);
        acc2[1] = __builtin_amdgcn_mfma_f32_32x32x16_bf16(a1, s0, acc2[1], 0, 0, 0);
      }
    }
  };

  stage(0);
  __syncthreads();
#pragma unroll 2
  for (int c = 0; c < 14; ++c) {
    if (c < 13) stage(c + 1);   // issue next chunk first
    mma(c);
    __syncthreads();            // drain (R4-proven)
  }

  // ---- epilogue ----
  const float* uf  = (const float*)(ws + UOFF);
  const float* wuf = (const float*)(ws + WUOFF);
  float wuv[2];
#pragma unroll
  for (int nt = 0; nt < 2; ++nt) wuv[nt] = wuf[nsl * 128 + wc * 64 + nt * 32 + l31];
  const float btv = BT[nsl * 64 + wc * 32 + l31];
  float* outm = out + (size_t)BATCH * 512;
#pragma unroll
  for (int mt = 0; mt < 2; ++mt)
#pragma unroll
    for (int reg = 0; reg < 16; ++reg) {
      const int rit = (reg & 3) + 8 * (reg >> 2) + 4 * kh;
      const size_t row = (size_t)(b0 + wr * 64 + mt * 32 + rit);
      const float uv = uf[row];
#pragma unroll
      for (int nt = 0; nt < 2; ++nt) {
        float v = acc[mt][nt][reg] + uv * wuv[nt];
        out[row * 512 + nsl * 128 + wc * 64 + nt * 32 + l31] =
            1.0f / (1.0f + __expf(-v));
      }
      outm[row * 256 + nsl * 64 + wc * 32 + l31] = acc2[mt][reg] + uv * btv;
    }
}

extern "C" void kernel_launch(void* const* d_in, const int* in_sizes, int n_in,
                              void* d_out, int out_size, void* d_ws, size_t ws_size,
                              hipStream_t stream) {
  const float* x  = (const float*)d_in[0];
  const float* h  = (const float*)d_in[1];
  const float* m  = (const float*)d_in[2];
  const float* Wx = (const float*)d_in[3];
  const float* Wh = (const float*)d_in[4];
  const float* Wm = (const float*)d_in[5];
  const float* ex = (const float*)d_in[6];
  const float* eh = (const float*)d_in[7];
  const float* em = (const float*)d_in[8];
  const float* AT = (const float*)d_in[9];
  const float* BT = (const float*)d_in[10];
  float* out = (float*)d_out;
  u16* ws = (u16*)d_ws;   // uses ~30.5 MB

  lmu_wpack<<<PACK_BLOCKS + WM2_BLOCKS, 256, 0, stream>>>(Wx, Wh, Wm, AT, BT, ws);
  lmu_prep<<<BATCH / 4, 256, 0, stream>>>(x, h, m, ex, eh, em, ws);
  lmu_gemm<<<512, 256, 0, stream>>>(ws, BT, out);
}